// Round 8
// baseline (529.559 us; speedup 1.0000x reference)
//
#include <hip/hip_runtime.h>

// Problem is fixed-shape: B=8192, N=4096, M=4096, G=512, CB=256.
#define B_DIM 8192
#define N_DIM 4096
#define M_DIM 4096
#define G_DIM 512

typedef short bf16x8 __attribute__((ext_vector_type(8)));
typedef float f32x4 __attribute__((ext_vector_type(4)));

typedef __attribute__((address_space(1))) const void gvoid_t;
typedef __attribute__((address_space(3))) void lvoid_t;

__device__ __forceinline__ void load_lds16(const void* g, void* l) {
    __builtin_amdgcn_global_load_lds((gvoid_t*)g, (lvoid_t*)l, 16, 0, 0);
}

// Generic->LDS addrspace cast; as3 pointers are 32-bit LDS byte offsets.
__device__ __forceinline__ unsigned lds_u32(const void* p) {
    return (unsigned)(unsigned long long)(lvoid_t*)p;
}

__device__ __forceinline__ unsigned short f2bf(float f) {
    union { float f; unsigned int u; } v; v.f = f;
    unsigned int u = v.u;
    unsigned int r = (u + 0x7fffu + ((u >> 16) & 1u)) >> 16;
    return (unsigned short)r;
}
__device__ __forceinline__ float bf2f(unsigned short s) {
    union { unsigned int u; float f; } v; v.u = ((unsigned int)s) << 16;
    return v.f;
}

// In-register H16 (unnormalized Hadamard over 16 values).
__device__ __forceinline__ void h16(float* v) {
#pragma unroll
    for (int h = 1; h < 16; h <<= 1) {
#pragma unroll
        for (int i = 0; i < 16; i++) {
            if (!(i & h)) {
                float a = v[i], b = v[i | h];
                v[i] = a + b;
                v[i | h] = a - b;
            }
        }
    }
}

// In-register H64 (unnormalized Hadamard over 64 values).
__device__ __forceinline__ void h64(float* v) {
#pragma unroll
    for (int h = 1; h < 64; h <<= 1) {
#pragma unroll
        for (int i = 0; i < 64; i++) {
            if (!(i & h)) {
                float a = v[i], b = v[i | h];
                v[i] = a + b;
                v[i | h] = a - b;
            }
        }
    }
}

// ---------------------------------------------------------------------------
// Kernel 1 (fused, R8): build W AND apply H64 over the LOW 6 bits of m.
// H_4096 = H_hi . H_lo (butterflies on disjoint bit-groups commute), so
// applying H_lo at build time and H_hi in a second kernel equals the old
// two-pass H. H_lo acts on CONTIGUOUS 64-row groups -> aligns with a build
// tile. Block = 64 rows x 256 cols:
//   - codebooks staged in LDS (256 x 9 pad, as before),
//   - build (cb1[q1]*ws + cb2[q2]*ws*irs) into f32 LDS tile [64][256],
//   - per-column in-register H64 (lanes read consecutive cols: conflict-free),
//   - pack bf16, int4 (16B/lane) coalesced stores.
// Deletes one full 64 MiB read+write of W vs the old build->hadw chain.
// ---------------------------------------------------------------------------
__global__ __launch_bounds__(256) void k_build_hlo(
    const int* __restrict__ q1, const int* __restrict__ q2,
    const float* __restrict__ cb1, const float* __restrict__ cb2,
    const float* __restrict__ wsp, const float* __restrict__ irsp,
    unsigned short* __restrict__ W) {
    __shared__ float c1[256 * 9];
    __shared__ float c2[256 * 9];
    __shared__ float tile[64 * 256];  // 64 KiB
    int t = threadIdx.x;
#pragma unroll
    for (int j = 0; j < 8; j++) {
        c1[t * 9 + j] = cb1[t * 8 + j];
        c2[t * 9 + j] = cb2[t * 8 + j];
    }
    __syncthreads();
    float ws = wsp[0];
    float irs = irsp[0] * ws;
    int ct = blockIdx.x;   // 0..15  column tile (256 cols)
    int h  = blockIdx.y;   // 0..63  row group (rows 64h..64h+63)
    int g0 = ct * 32;      // group base (col = g*8)
    int rr = t >> 5;       // 0..7
    int j  = t & 31;       // col-chunk within tile
    // build: rows rr+8p, 8 cols per thread per row
#pragma unroll
    for (int p = 0; p < 8; p++) {
        int row = rr + 8 * p;
        int m = 64 * h + row;
        int i1 = q1[m * G_DIM + g0 + j] * 9;
        int i2 = q2[m * G_DIM + g0 + j] * 9;
        float* dst = &tile[row * 256 + 8 * j];
#pragma unroll
        for (int i = 0; i < 8; i++) dst[i] = c1[i1 + i] * ws + c2[i2 + i] * irs;
    }
    __syncthreads();
    // H64 over rows (the lo digit) for column c = t
    {
        float v[64];
#pragma unroll
        for (int r2 = 0; r2 < 64; r2++) v[r2] = tile[r2 * 256 + t];
        h64(v);
#pragma unroll
        for (int r2 = 0; r2 < 64; r2++) tile[r2 * 256 + t] = v[r2];
    }
    __syncthreads();
    // writeback: bf16 pack, int4 stores
#pragma unroll
    for (int p = 0; p < 8; p++) {
        int row = rr + 8 * p;
        int m = 64 * h + row;
        union { unsigned short s[8]; int4 v4; } o;
#pragma unroll
        for (int i = 0; i < 8; i++) o.s[i] = f2bf(tile[row * 256 + 8 * j + i]);
        *(int4*)(W + (size_t)m * N_DIM + ct * 256 + 8 * j) = o.v4;
    }
}

// ---------------------------------------------------------------------------
// Kernel 1b (R8): H64 over the HIGH 6 bits of m (rows lo + 64*hi, stride 64),
// in place, 1/64 normalization folded in. LDS-tile version: int4 (16B/lane)
// coalesced loads/stores replace the old 64 scalar 2B accesses per thread.
// Block = (lo, col-tile): rows {lo+64*hi}, cols [ct*256, ct*256+256).
// Disjoint tiles across blocks -> in-place safe.
// ---------------------------------------------------------------------------
__global__ __launch_bounds__(256) void k_hadw_hi(unsigned short* __restrict__ W) {
    __shared__ float tile[64 * 256];  // 64 KiB -> 2 blocks/CU
    int t = threadIdx.x;
    int ct = blockIdx.x;  // 0..15
    int lo = blockIdx.y;  // 0..63
    int rr = t >> 5;
    int j = t & 31;
#pragma unroll
    for (int p = 0; p < 8; p++) {
        int hi = rr + 8 * p;
        size_t m = (size_t)lo + 64 * hi;
        union { int4 v4; unsigned short s[8]; } u;
        u.v4 = *(const int4*)(W + m * N_DIM + ct * 256 + 8 * j);
#pragma unroll
        for (int i = 0; i < 8; i++) tile[hi * 256 + 8 * j + i] = bf2f(u.s[i]);
    }
    __syncthreads();
    {
        float v[64];
#pragma unroll
        for (int hi = 0; hi < 64; hi++) v[hi] = tile[hi * 256 + t];
        h64(v);
#pragma unroll
        for (int hi = 0; hi < 64; hi++) tile[hi * 256 + t] = v[hi] * 0.015625f;
    }
    __syncthreads();
#pragma unroll
    for (int p = 0; p < 8; p++) {
        int hi = rr + 8 * p;
        size_t m = (size_t)lo + 64 * hi;
        union { unsigned short s[8]; int4 v4; } o;
#pragma unroll
        for (int i = 0; i < 8; i++) o.s[i] = f2bf(tile[hi * 256 + 8 * j + i]);
        *(int4*)(W + m * N_DIM + ct * 256 + 8 * j) = o.v4;
    }
}

// ---------------------------------------------------------------------------
// Kernel 2: x_rht = fht(x * SV) -> bf16 (R1 256-thread version, known-best).
// ---------------------------------------------------------------------------
__global__ __launch_bounds__(256) void k_rht_in(
    const float* __restrict__ x, const float* __restrict__ SV,
    unsigned short* __restrict__ out) {
    __shared__ float lds[4352];  // f(n) = n + (n>>4), max 4350
    int row = blockIdx.x;
    int t = threadIdx.x;
    const float* xr = x + (size_t)row * N_DIM;
    float v[16];
    // phase A: n = t + 256r
#pragma unroll
    for (int r = 0; r < 16; r++) {
        int n = t + (r << 8);
        v[r] = xr[n] * SV[n] * 0.015625f;
    }
    h16(v);
#pragma unroll
    for (int r = 0; r < 16; r++) { int n = t + (r << 8); lds[n + (n >> 4)] = v[r]; }
    __syncthreads();
    // phase B: n = 16t + r
#pragma unroll
    for (int r = 0; r < 16; r++) { int n = (t << 4) + r; v[r] = lds[n + (n >> 4)]; }
    h16(v);
#pragma unroll
    for (int r = 0; r < 16; r++) { int n = (t << 4) + r; lds[n + (n >> 4)] = v[r]; }
    __syncthreads();
    // phase C: n = (t&15) | (r<<4) | ((t>>4)<<8)
#pragma unroll
    for (int r = 0; r < 16; r++) {
        int n = (t & 15) | (r << 4) | ((t >> 4) << 8);
        v[r] = lds[n + (n >> 4)];
    }
    h16(v);
#pragma unroll
    for (int r = 0; r < 16; r++) {
        int n = (t & 15) | (r << 4) | ((t >> 4) << 8);
        lds[n + (n >> 4)] = v[r];
    }
    __syncthreads();
    unsigned short* orow = out + (size_t)row * N_DIM;
#pragma unroll
    for (int r = 0; r < 16; r++) {
        int n = t + (r << 8);
        orow[n] = f2bf(lds[n + (n >> 4)]);
    }
}

// ---------------------------------------------------------------------------
// Kernel 3 (v6b, R7-verified): y[b,m] = SU[m]*dot(x_rht[b,:], W''[m,:]) (NT)
// BYTE-IDENTICAL to round 7 (246 us steady, MfmaUtil 52%, 0 conflicts).
// ---------------------------------------------------------------------------
#define DSR(D, A, OFF) \
    asm volatile("ds_read_b128 %0, %1 offset:" #OFF : "=v"(D) : "v"(A))
#define SB0() __builtin_amdgcn_sched_barrier(0)
#define SGB(M, N) __builtin_amdgcn_sched_group_barrier((M), (N), 0)

__global__ __launch_bounds__(512, 2) void k_gemm(
    const unsigned short* __restrict__ A,   // (B_DIM, N_DIM) bf16
    const unsigned short* __restrict__ Bw,  // (M_DIM, N_DIM) bf16  (= W'')
    const float* __restrict__ SU,
    float* __restrict__ C) {                // (B_DIM, M_DIM) f32
    __shared__ __align__(16) unsigned short lds[4 * 16384];  // 128 KiB

    int t = threadIdx.x;
    int w = t >> 6;   // wave 0..7
    int l = t & 63;

    // XCD-aware tile mapping (bijective, 512 % 8 == 0) — R1 map.
    int lin = blockIdx.x;
    int xcd = lin & 7;
    int idx = lin >> 3;             // 0..63
    int bn = xcd * 2 + (idx >> 5);  // 0..15  (M tiles)
    int bm = idx & 31;              // 0..31  (B tiles)

    // staging: lane l writes LDS slot (row w*16 + l>>2, chunk l&3) of a
    // 128-row half; inverse-swizzled global source uses lx = l ^ (l>>3).
    int lx = l ^ (l >> 3);
    const unsigned short* aS0 =
        A + (size_t)(bm * 256 + w * 16 + (lx >> 2)) * N_DIM + (lx & 3) * 8;
    const unsigned short* aS1 = aS0 + (size_t)128 * N_DIM;
    const unsigned short* bS0 =
        Bw + (size_t)(bn * 256 + w * 16 + (lx >> 2)) * N_DIM + (lx & 3) * 8;
    const unsigned short* bS1 = bS0 + (size_t)128 * N_DIM;

    // fragment read byte-addresses (swizzled), as 32-bit LDS offsets
    int wm = w >> 2;   // 0..1  (M half)
    int wn = w & 3;    // 0..3  (N quarter)
    int quad = l >> 4;
    int ln = l & 15;
    unsigned ldsU = lds_u32(lds);
    unsigned aByte = ldsU +
        (unsigned)(((((wm * 128) + ln) << 6) | (quad << 4)) ^ ((ln >> 1) << 4));
    unsigned bByte = ldsU + 16384u +
        (unsigned)(((((wn * 64) + ln) << 6) | (quad << 4)) ^ ((ln >> 1) << 4));

    f32x4 acc[8][4];
#pragma unroll
    for (int i = 0; i < 8; i++)
#pragma unroll
        for (int j = 0; j < 4; j++) {
            f32x4 z = {0.f, 0.f, 0.f, 0.f};
            acc[i][j] = z;
        }

#define STAGE(KT) do {                                              \
        int kt_ = (KT);                                             \
        int ks_ = kt_ < 127 ? kt_ : 127;                            \
        unsigned short* d_ = lds + ((unsigned)kt_ & 3u) * 16384 + w * 512; \
        load_lds16(aS0 + ks_ * 32, d_);                             \
        load_lds16(aS1 + ks_ * 32, d_ + 4096);                      \
        load_lds16(bS0 + ks_ * 32, d_ + 8192);                      \
        load_lds16(bS1 + ks_ * 32, d_ + 12288);                     \
    } while (0)

#define GROUP(I, BC) do {                                           \
        acc[I][0] = __builtin_amdgcn_mfma_f32_16x16x32_bf16(        \
            af[I], BC[0], acc[I][0], 0, 0, 0);                      \
        acc[I][1] = __builtin_amdgcn_mfma_f32_16x16x32_bf16(        \
            af[I], BC[1], acc[I][1], 0, 0, 0);                      \
        acc[I][2] = __builtin_amdgcn_mfma_f32_16x16x32_bf16(        \
            af[I], BC[2], acc[I][2], 0, 0, 0);                      \
        acc[I][3] = __builtin_amdgcn_mfma_f32_16x16x32_bf16(        \
            af[I], BC[3], acc[I][3], 0, 0, 0);                      \
    } while (0)

    // BODY(k): MFMAs consume tile k (af + BC, loaded in iter k-1);
    // interleaved reads fill tile k+1 (af overwritten group-by-group + BN).
#define BODY(K, BC, BN) do {                                        \
        asm volatile("s_waitcnt lgkmcnt(0)");                       \
        SB0();  /* rule 18: MFMAs stay below; tile-K frags arrived */ \
        STAGE((K) + 3);                                             \
        unsigned aun = aByte + ((unsigned)((K) + 1) & 3u) * 32768u; \
        unsigned bun = bByte + ((unsigned)((K) + 1) & 3u) * 32768u; \
        SGB(0x10, 4);  /* 4 stage VMEM first */                     \
        GROUP(0, BC); DSR(af[0], aun, 0);    DSR(BN[0], bun, 0);    \
        SGB(0x8, 4); SGB(0x100, 2);                                 \
        GROUP(1, BC); DSR(af[1], aun, 1024); DSR(BN[1], bun, 1024); \
        SGB(0x8, 4); SGB(0x100, 2);                                 \
        GROUP(2, BC); DSR(af[2], aun, 2048); DSR(BN[2], bun, 2048); \
        SGB(0x8, 4); SGB(0x100, 2);                                 \
        GROUP(3, BC); DSR(af[3], aun, 3072); DSR(BN[3], bun, 3072); \
        SGB(0x8, 4); SGB(0x100, 2);                                 \
        GROUP(4, BC); DSR(af[4], aun, 4096);                        \
        SGB(0x8, 4); SGB(0x100, 1);                                 \
        GROUP(5, BC); DSR(af[5], aun, 5120);                        \
        SGB(0x8, 4); SGB(0x100, 1);                                 \
        GROUP(6, BC); DSR(af[6], aun, 6144);                        \
        SGB(0x8, 4); SGB(0x100, 1);                                 \
        GROUP(7, BC); DSR(af[7], aun, 7168);                        \
        SGB(0x8, 4); SGB(0x100, 1);                                 \
        asm volatile("s_waitcnt vmcnt(4)");  /* tile K+2 landed; >0 */ \
        asm volatile("" ::: "memory");                              \
        __builtin_amdgcn_s_barrier();                               \
        asm volatile("" ::: "memory");                              \
    } while (0)

    bf16x8 af[8], bfrA[4], bfrB[4];

    // prologue: stage 0..2; vmcnt(4) => tiles 0 AND 1 landed (only
    // STAGE(2) may be in flight) — BODY(0) reads tile 1 mid-body.
    STAGE(0);
    STAGE(1);
    STAGE(2);
    asm volatile("s_waitcnt vmcnt(4)");
    __builtin_amdgcn_s_barrier();
    asm volatile("" ::: "memory");
    {
        unsigned au0 = aByte;
        unsigned bu0 = bByte;
        DSR(af[0], au0, 0);
        DSR(af[1], au0, 1024);
        DSR(af[2], au0, 2048);
        DSR(af[3], au0, 3072);
        DSR(af[4], au0, 4096);
        DSR(af[5], au0, 5120);
        DSR(af[6], au0, 6144);
        DSR(af[7], au0, 7168);
        DSR(bfrA[0], bu0, 0);
        DSR(bfrA[1], bu0, 1024);
        DSR(bfrA[2], bu0, 2048);
        DSR(bfrA[3], bu0, 3072);
    }

    for (int k = 0; k < N_DIM / 32; k += 2) {
        BODY(k, bfrA, bfrB);
        BODY(k + 1, bfrB, bfrA);
    }
    asm volatile("s_waitcnt vmcnt(0) lgkmcnt(0)");  // drain tail dummies

    // epilogue: C/D layout col=lane&15, row=quad*4+reg (m89/m91-verified)
#pragma unroll
    for (int j = 0; j < 4; j++) {
        int col = bn * 256 + wn * 64 + j * 16 + ln;
        float su = SU[col];
#pragma unroll
        for (int i = 0; i < 8; i++) {
#pragma unroll
            for (int r = 0; r < 4; r++) {
                int rowg = bm * 256 + wm * 128 + i * 16 + quad * 4 + r;
                C[(size_t)rowg * M_DIM + col] = acc[i][j][r] * su;
            }
        }
    }
#undef STAGE
#undef GROUP
#undef BODY
}

extern "C" void kernel_launch(void* const* d_in, const int* in_sizes, int n_in,
                              void* d_out, int out_size, void* d_ws, size_t ws_size,
                              hipStream_t stream) {
    const float* x    = (const float*)d_in[0];
    const int*   q1   = (const int*)d_in[1];
    const int*   q2   = (const int*)d_in[2];
    const float* SU   = (const float*)d_in[3];
    const float* SV   = (const float*)d_in[4];
    const float* cb1  = (const float*)d_in[5];
    const float* cb2  = (const float*)d_in[6];
    const float* wsp  = (const float*)d_in[7];
    const float* irsp = (const float*)d_in[8];
    float* out = (float*)d_out;  // reference output dtype: float32

    // workspace: x_rht bf16 (64MiB) | W bf16 (32MiB)  => 96MiB total
    unsigned short* xrht = (unsigned short*)d_ws;
    unsigned short* Wb   = xrht + (size_t)B_DIM * N_DIM;

    // W'' = (1/64) * H_hi(H_lo(W)) — fused build+H_lo, then LDS-tile H_hi.
    k_build_hlo<<<dim3(16, 64), dim3(256), 0, stream>>>(
        q1, q2, cb1, cb2, wsp, irsp, Wb);
    k_hadw_hi<<<dim3(16, 64), dim3(256), 0, stream>>>(Wb);
    k_rht_in<<<dim3(B_DIM), dim3(256), 0, stream>>>(x, SV, xrht);
    k_gemm<<<dim3(512), dim3(512), 0, stream>>>(xrht, Wb, SU, out);
}